// Round 4
// baseline (21.094 us; speedup 1.0000x reference)
//
#include <hip/hip_runtime.h>
#include <math.h>

#define H_OUT 225
#define W_OUT 400
#define NPIX (H_OUT * W_OUT)      // 90000
#define NBOX 128
#define TW 16
#define TH 16
#define TX 25                      // ceil(400/16)
#define TY 15                      // ceil(225/16)
#define NBLK (TX * TY)             // 375
#define BS  256

// EPS64 = np.finfo(np.float64).eps
#define EPS64F 2.2204460492503131e-16f

__global__ __launch_bounds__(BS) void segloss_fused(
    const float* __restrict__ boxes,   // (128,4) [u1,v1,u2,v2]
    const float* __restrict__ pred,    // (1,2,225,400)
    float* __restrict__ part,          // 3*NBLK partials in d_ws
    unsigned* __restrict__ cnt,        // completion counter in d_ws (memset to 0 per call)
    float* __restrict__ out)
{
    __shared__ unsigned long long smask[2];
    __shared__ int   nsel;
    __shared__ int   sbx[NBOX], sby[NBOX], sr[NBOX], scol[NBOX];
    __shared__ float s2s[NBOX];        // 2*sigma^2

    const int t = threadIdx.x;
    const int tileX = blockIdx.x % TX;
    const int tileY = blockIdx.x / TX;

    const int x = tileX * TW + (t & (TW - 1));
    const int y = tileY * TH + (t >> 4);
    const bool valid = (x < W_OUT) && (y < H_OUT);
    const int i = valid ? (y * W_OUT + x) : 0;

    // prefetch focal-loss inputs so global latency overlaps the box work
    const float pa = pred[i];
    const float pb = pred[NPIX + i];

    // tile bbox in source (900x1600) coordinates; pixel p samples source 4*p
    const int x0s = tileX * TW * 4, x1s = x0s + (TW - 1) * 4;
    const int y0s = tileY * TH * 4, y1s = y0s + (TH - 1) * 4;

    // ---- Stage A: per-box tile intersection + deterministic compaction ----
    bool keep = false;
    int bx = 0, by = 0, r = 0, col = 0;
    float two_s2 = 0.0f;
    if (t < NBOX) {
        float u1 = boxes[t * 4 + 0];
        float v1 = boxes[t * 4 + 1];
        float u2 = boxes[t * 4 + 2];
        float v2 = boxes[t * 4 + 3];
        float hw = fabsf((u1 - u2) * 0.5f);
        float hh = fabsf((v1 - v2) * 0.5f);
        r   = (int)fmaxf(hw, hh);          // trunc, positive
        bx  = (int)((u1 + u2) * 0.5f);     // trunc
        by  = (int)((v1 + v2) * 0.5f);
        col = (hw <= hh) ? 1 : 0;
        float sigma = (float)(2 * r + 1) / 6.0f;
        two_s2 = 2.0f * sigma * sigma;
        keep = (bx + r >= x0s) && (bx - r <= x1s) &&
               (by + r >= y0s) && (by - r <= y1s);
    }
    unsigned long long m = __ballot(keep);
    if (t < NBOX && (t & 63) == 0) smask[t >> 6] = m;
    __syncthreads();
    if (t < NBOX) {
        const int w = t >> 6, lane = t & 63;
        const unsigned long long lm = smask[w];
        int off = __popcll(lm & ((1ull << lane) - 1ull));
        if (w) off += __popcll(smask[0]);
        if (keep) {
            sbx[off] = bx; sby[off] = by; sr[off] = r;
            scol[off] = col; s2s[off] = two_s2;
        }
        if (t == 0) nsel = __popcll(smask[0]) + __popcll(smask[1]);
    }
    __syncthreads();

    // ---- Stage B: evaluate only surviving boxes ----
    float sfg = 0.0f, sbg = 0.0f, snp = 0.0f;
    if (valid) {
        const int px = x * 4;
        const int py = y * 4;
        float acc = 0.0f;
        const int ns = nsel;
        for (int k = 0; k < ns; ++k) {
            const int dx = px - sbx[k];
            const int dy = py - sby[k];
            const int rr = sr[k];
            if (dx > rr || dx < -rr || dy > rr || dy < -rr) continue;
            const int hl  = rr >> 1;          // r//2
            const int hh2 = (rr + 1) >> 1;    // ceil(r/2)
            bool band;
            if (scol[k]) {
                band = (dx < -hl) || (dx >= hh2);
            } else {
                band = (dy < -hh2) || (dy >= hh2);
            }
            if (band) continue;
            const float d2 = (float)(dx * dx + dy * dy);
            const float g  = expf(-d2 / s2s[k]);     // identical arithmetic to R2 (absmax 0)
            if (g >= EPS64F) acc += g;
        }

        const float fgs = fminf(fmaxf(acc, 0.0f), 1.0f);
        const bool  fgb = fgs > 0.5f;
        const float bgm = fgb ? 0.0f : 1.0f;
        const float w   = fgb ? 13.0f : 1.0f;
        const int   tgt = (int)fgs;           // 1 only where saturated to exactly 1.0

        const float mx  = fmaxf(pa, pb);
        const float lse = mx + logf(expf(pa - mx) + expf(pb - mx));
        const float logpt = (tgt ? pb : pa) - lse;
        const float pt = expf(logpt);
        const float om = 1.0f - pt;
        const float loss = -0.25f * om * om * logpt * w;

        sfg = loss * fgs;
        sbg = loss * bgm;
        snp = fgs + bgm;
    }

    // block reduction: wave shuffle + cross-wave LDS
    for (int o = 32; o > 0; o >>= 1) {
        sfg += __shfl_down(sfg, o);
        sbg += __shfl_down(sbg, o);
        snp += __shfl_down(snp, o);
    }
    __shared__ float rfg[BS / 64], rbg[BS / 64], rnp[BS / 64];
    const int wave = t >> 6, lane = t & 63;
    if (lane == 0) { rfg[wave] = sfg; rbg[wave] = sbg; rnp[wave] = snp; }
    __syncthreads();
    if (t == 0) {
        float a1 = 0.f, a2 = 0.f, a3 = 0.f;
        for (int wv = 0; wv < BS / 64; ++wv) { a1 += rfg[wv]; a2 += rbg[wv]; a3 += rnp[wv]; }
        // agent-scope atomic stores so the last block (any XCD) sees them
        __hip_atomic_store(&part[blockIdx.x],            a1, __ATOMIC_RELAXED, __HIP_MEMORY_SCOPE_AGENT);
        __hip_atomic_store(&part[NBLK + blockIdx.x],     a2, __ATOMIC_RELAXED, __HIP_MEMORY_SCOPE_AGENT);
        __hip_atomic_store(&part[2 * NBLK + blockIdx.x], a3, __ATOMIC_RELAXED, __HIP_MEMORY_SCOPE_AGENT);
    }

    // ---- last-block-done final reduction (deterministic: fixed read order) ----
    __shared__ int isLast;
    __syncthreads();                 // ensure the partial stores above are issued
    if (t == 0) {
        __builtin_amdgcn_fence(__ATOMIC_RELEASE, "agent");
        unsigned old = __hip_atomic_fetch_add(cnt, 1u, __ATOMIC_ACQ_REL, __HIP_MEMORY_SCOPE_AGENT);
        isLast = (old == NBLK - 1) ? 1 : 0;
    }
    __syncthreads();
    if (isLast) {
        __builtin_amdgcn_fence(__ATOMIC_ACQUIRE, "agent");
        float f1 = 0.f, f2 = 0.f, f3 = 0.f;
        for (int b = t; b < NBLK; b += BS) {
            f1 += __hip_atomic_load(&part[b],            __ATOMIC_RELAXED, __HIP_MEMORY_SCOPE_AGENT);
            f2 += __hip_atomic_load(&part[NBLK + b],     __ATOMIC_RELAXED, __HIP_MEMORY_SCOPE_AGENT);
            f3 += __hip_atomic_load(&part[2 * NBLK + b], __ATOMIC_RELAXED, __HIP_MEMORY_SCOPE_AGENT);
        }
        for (int o = 32; o > 0; o >>= 1) {
            f1 += __shfl_down(f1, o);
            f2 += __shfl_down(f2, o);
            f3 += __shfl_down(f3, o);
        }
        if (lane == 0) { rfg[wave] = f1; rbg[wave] = f2; rnp[wave] = f3; }
        __syncthreads();
        if (t == 0) {
            float a1 = 0.f, a2 = 0.f, a3 = 0.f;
            for (int wv = 0; wv < BS / 64; ++wv) { a1 += rfg[wv]; a2 += rbg[wv]; a3 += rnp[wv]; }
            out[0] = (a1 + a2) / a3;     // (fg_loss + bg_loss), WEIGHT = 1
        }
    }
}

extern "C" void kernel_launch(void* const* d_in, const int* in_sizes, int n_in,
                              void* d_out, int out_size, void* d_ws, size_t ws_size,
                              hipStream_t stream) {
    const float* boxes = (const float*)d_in[0];   // gt_boxes2d (128,4)
    // d_in[1] = images (900,1600): only its shape is used by the reference
    const float* pred  = (const float*)d_in[2];   // fg_pred (1,2,225,400)
    float* out  = (float*)d_out;
    float* part = (float*)d_ws;                   // 3*NBLK floats = 4500 B
    unsigned* cnt = (unsigned*)((char*)d_ws + 4608);

    // reset completion counter (graph-capturable memset node; handles 0xAA poison)
    (void)hipMemsetAsync(cnt, 0, sizeof(unsigned), stream);
    segloss_fused<<<NBLK, BS, 0, stream>>>(boxes, pred, part, cnt, out);
}

// Round 5
// 18.376 us; speedup vs baseline: 1.1479x; 1.1479x over previous
//
#include <hip/hip_runtime.h>
#include <math.h>

#define H_OUT 225
#define W_OUT 400
#define NPIX (H_OUT * W_OUT)      // 90000
#define NBOX 128
#define TW 64                      // tile width in output pixels
#define TH 64                      // tile height
#define TX 7                       // ceil(400/64)
#define TY 4                       // ceil(225/64)
#define NBLK (TX * TY)             // 28 blocks
#define BS  1024                   // 16 waves; each thread does 4 pixels along x

// EPS64 = np.finfo(np.float64).eps
#define EPS64F 2.2204460492503131e-16f

__global__ __launch_bounds__(BS) void segloss_main(
    const float* __restrict__ boxes,   // (128,4) [u1,v1,u2,v2]
    const float* __restrict__ pred,    // (1,2,225,400)
    float* __restrict__ part)          // 3*NBLK partials: [sfg | sbg | snp]
{
    __shared__ unsigned long long smask[2];
    __shared__ int   nsel;
    __shared__ int   sbx[NBOX], sby[NBOX], sr[NBOX], scol[NBOX];
    __shared__ float s2s[NBOX];        // 2*sigma^2

    const int t = threadIdx.x;
    const int tileX = blockIdx.x % TX;
    const int tileY = blockIdx.x / TX;

    // thread -> 4 consecutive output pixels: (y, x0..x0+3)
    const int x0 = tileX * TW + (t & 15) * 4;
    const int y  = tileY * TH + (t >> 4);
    const bool row_ok = (y < H_OUT);

    // vectorized prefetch of focal-loss inputs (16B aligned: x0 % 4 == 0, W=400 % 4 == 0)
    float pa[4], pb[4];
    {
        const int i0 = y * W_OUT + x0;
        if (row_ok && x0 + 3 < W_OUT) {
            const float4 va = *reinterpret_cast<const float4*>(pred + i0);
            const float4 vb = *reinterpret_cast<const float4*>(pred + NPIX + i0);
            pa[0] = va.x; pa[1] = va.y; pa[2] = va.z; pa[3] = va.w;
            pb[0] = vb.x; pb[1] = vb.y; pb[2] = vb.z; pb[3] = vb.w;
        } else {
            for (int j = 0; j < 4; ++j) {
                const bool ok = row_ok && (x0 + j) < W_OUT;
                const int ij = ok ? (i0 + j) : 0;
                pa[j] = ok ? pred[ij] : 0.0f;
                pb[j] = ok ? pred[NPIX + ij] : 0.0f;
            }
        }
    }

    // tile bbox in source (900x1600) coordinates; pixel p samples source 4*p
    const int x0s = tileX * TW * 4, x1s = x0s + (TW - 1) * 4;
    const int y0s = tileY * TH * 4, y1s = y0s + (TH - 1) * 4;

    // ---- Stage A: per-box tile intersection + deterministic compaction ----
    bool keep = false;
    int bx = 0, by = 0, r = 0, col = 0;
    float two_s2 = 0.0f;
    if (t < NBOX) {
        float u1 = boxes[t * 4 + 0];
        float v1 = boxes[t * 4 + 1];
        float u2 = boxes[t * 4 + 2];
        float v2 = boxes[t * 4 + 3];
        float hw = fabsf((u1 - u2) * 0.5f);
        float hh = fabsf((v1 - v2) * 0.5f);
        r   = (int)fmaxf(hw, hh);          // trunc, positive
        bx  = (int)((u1 + u2) * 0.5f);     // trunc
        by  = (int)((v1 + v2) * 0.5f);
        col = (hw <= hh) ? 1 : 0;
        float sigma = (float)(2 * r + 1) / 6.0f;
        two_s2 = 2.0f * sigma * sigma;
        keep = (bx + r >= x0s) && (bx - r <= x1s) &&
               (by + r >= y0s) && (by - r <= y1s);
    }
    unsigned long long m = __ballot(keep);
    if (t < NBOX && (t & 63) == 0) smask[t >> 6] = m;
    __syncthreads();
    if (t < NBOX) {
        const int w = t >> 6, lane = t & 63;
        const unsigned long long lm = smask[w];
        int off = __popcll(lm & ((1ull << lane) - 1ull));
        if (w) off += __popcll(smask[0]);
        if (keep) {
            sbx[off] = bx; sby[off] = by; sr[off] = r;
            scol[off] = col; s2s[off] = two_s2;
        }
        if (t == 0) nsel = __popcll(smask[0]) + __popcll(smask[1]);
    }
    __syncthreads();

    // ---- Stage B: evaluate surviving boxes for this thread's 4 pixels ----
    float acc[4] = {0.0f, 0.0f, 0.0f, 0.0f};
    if (row_ok && x0 < W_OUT) {
        const int py = y * 4;
        const int ns = nsel;
        for (int k = 0; k < ns; ++k) {
            const int dy = py - sby[k];
            const int rr = sr[k];
            if (dy > rr || dy < -rr) continue;
            const int hl  = rr >> 1;          // r//2
            const int hh2 = (rr + 1) >> 1;    // ceil(r/2)
            const int cl  = scol[k];
            if (!cl) {
                // row band depends only on dy: zero rows outside [y-hh2+1 .. y+hh2-1] within radius
                if (dy < -hh2 || dy >= hh2) continue;
            }
            const float ts2 = s2s[k];
            const int bxk = sbx[k];
            const float fdy2 = (float)(dy * dy);
            #pragma unroll
            for (int j = 0; j < 4; ++j) {
                const int dx = (x0 + j) * 4 - bxk;
                if (dx > rr || dx < -rr) continue;
                if (cl && (dx < -hl || dx >= hh2)) continue;
                const float d2 = (float)(dx * dx) + fdy2;
                const float g  = expf(-d2 / ts2);     // identical arithmetic to R2 (absmax 0)
                if (g >= EPS64F) acc[j] += g;
            }
        }
    }

    // ---- per-pixel loss, summed over this thread's valid pixels ----
    float sfg = 0.0f, sbg = 0.0f, snp = 0.0f;
    #pragma unroll
    for (int j = 0; j < 4; ++j) {
        const bool ok = row_ok && (x0 + j) < W_OUT;
        if (!ok) continue;
        const float fgs = fminf(fmaxf(acc[j], 0.0f), 1.0f);
        const bool  fgb = fgs > 0.5f;
        const float bgm = fgb ? 0.0f : 1.0f;
        const float w   = fgb ? 13.0f : 1.0f;
        const int   tgt = (int)fgs;           // 1 only where saturated to exactly 1.0

        const float mx  = fmaxf(pa[j], pb[j]);
        const float lse = mx + logf(expf(pa[j] - mx) + expf(pb[j] - mx));
        const float logpt = (tgt ? pb[j] : pa[j]) - lse;
        const float pt = expf(logpt);
        const float om = 1.0f - pt;
        const float loss = -0.25f * om * om * logpt * w;

        sfg += loss * fgs;
        sbg += loss * bgm;
        snp += fgs + bgm;
    }

    // block reduction: wave shuffle + cross-wave LDS (16 waves)
    for (int o = 32; o > 0; o >>= 1) {
        sfg += __shfl_down(sfg, o);
        sbg += __shfl_down(sbg, o);
        snp += __shfl_down(snp, o);
    }
    __shared__ float rfg[BS / 64], rbg[BS / 64], rnp[BS / 64];
    const int wave = t >> 6, lane = t & 63;
    if (lane == 0) { rfg[wave] = sfg; rbg[wave] = sbg; rnp[wave] = snp; }
    __syncthreads();
    if (t == 0) {
        float a1 = 0.f, a2 = 0.f, a3 = 0.f;
        for (int wv = 0; wv < BS / 64; ++wv) { a1 += rfg[wv]; a2 += rbg[wv]; a3 += rnp[wv]; }
        part[blockIdx.x]            = a1;
        part[NBLK + blockIdx.x]     = a2;
        part[2 * NBLK + blockIdx.x] = a3;
    }
}

__global__ __launch_bounds__(64) void segloss_final(
    const float* __restrict__ part, float* __restrict__ out)
{
    const int t = threadIdx.x;     // one wave
    float sfg = 0.0f, sbg = 0.0f, snp = 0.0f;
    if (t < NBLK) {
        sfg = part[t];
        sbg = part[NBLK + t];
        snp = part[2 * NBLK + t];
    }
    for (int o = 32; o > 0; o >>= 1) {
        sfg += __shfl_down(sfg, o);
        sbg += __shfl_down(sbg, o);
        snp += __shfl_down(snp, o);
    }
    if (t == 0) out[0] = (sfg + sbg) / snp;   // (fg_loss + bg_loss), WEIGHT = 1
}

extern "C" void kernel_launch(void* const* d_in, const int* in_sizes, int n_in,
                              void* d_out, int out_size, void* d_ws, size_t ws_size,
                              hipStream_t stream) {
    const float* boxes = (const float*)d_in[0];   // gt_boxes2d (128,4)
    // d_in[1] = images (900,1600): only its shape is used by the reference
    const float* pred  = (const float*)d_in[2];   // fg_pred (1,2,225,400)
    float* out  = (float*)d_out;
    float* part = (float*)d_ws;                   // 3*NBLK floats = 336 B

    segloss_main<<<NBLK, BS, 0, stream>>>(boxes, pred, part);
    segloss_final<<<1, 64, 0, stream>>>(part, out);
}

// Round 6
// 15.520 us; speedup vs baseline: 1.3592x; 1.1840x over previous
//
#include <hip/hip_runtime.h>
#include <math.h>

#define H_OUT 225
#define W_OUT 400
#define NPIX (H_OUT * W_OUT)      // 90000
#define NBOX 128
#define TW 32                      // tile width in output pixels
#define TH 32                      // tile height
#define TX 13                      // ceil(400/32)
#define TY 8                       // ceil(225/32)
#define NBLK (TX * TY)             // 104 blocks
#define BS  256                    // 4 waves; each thread does 4 pixels along x

// EPS64 = np.finfo(np.float64).eps
#define EPS64F 2.2204460492503131e-16f

__global__ __launch_bounds__(BS) void segloss_main(
    const float* __restrict__ boxes,   // (128,4) [u1,v1,u2,v2]
    const float* __restrict__ pred,    // (1,2,225,400)
    float* __restrict__ part)          // 3*NBLK partials: [sfg | sbg | snp]
{
    __shared__ unsigned long long smask[2];
    __shared__ int   nsel;
    __shared__ int   sbx[NBOX], sby[NBOX], sr[NBOX], scol[NBOX];
    __shared__ float s2s[NBOX];        // 2*sigma^2

    const int t = threadIdx.x;
    const int tileX = blockIdx.x % TX;
    const int tileY = blockIdx.x / TX;

    // thread -> 4 consecutive output pixels: (y, x0..x0+3)
    const int x0 = tileX * TW + (t & 7) * 4;
    const int y  = tileY * TH + (t >> 3);
    const bool row_ok = (y < H_OUT);

    // vectorized prefetch of focal-loss inputs (x0 % 4 == 0 -> 16B aligned)
    float pa[4], pb[4];
    {
        const int i0 = y * W_OUT + x0;
        if (row_ok && x0 + 3 < W_OUT) {
            const float4 va = *reinterpret_cast<const float4*>(pred + i0);
            const float4 vb = *reinterpret_cast<const float4*>(pred + NPIX + i0);
            pa[0] = va.x; pa[1] = va.y; pa[2] = va.z; pa[3] = va.w;
            pb[0] = vb.x; pb[1] = vb.y; pb[2] = vb.z; pb[3] = vb.w;
        } else {
            for (int j = 0; j < 4; ++j) {
                const bool ok = row_ok && (x0 + j) < W_OUT;
                const int ij = ok ? (i0 + j) : 0;
                pa[j] = ok ? pred[ij] : 0.0f;
                pb[j] = ok ? pred[NPIX + ij] : 0.0f;
            }
        }
    }

    // tile bbox in source (900x1600) coordinates; pixel p samples source 4*p
    const int x0s = tileX * TW * 4, x1s = x0s + (TW - 1) * 4;
    const int y0s = tileY * TH * 4, y1s = y0s + (TH - 1) * 4;

    // ---- Stage A: per-box tile intersection + deterministic compaction ----
    bool keep = false;
    int bx = 0, by = 0, r = 0, col = 0;
    float two_s2 = 0.0f;
    if (t < NBOX) {
        float u1 = boxes[t * 4 + 0];
        float v1 = boxes[t * 4 + 1];
        float u2 = boxes[t * 4 + 2];
        float v2 = boxes[t * 4 + 3];
        float hw = fabsf((u1 - u2) * 0.5f);
        float hh = fabsf((v1 - v2) * 0.5f);
        r   = (int)fmaxf(hw, hh);          // trunc, positive
        bx  = (int)((u1 + u2) * 0.5f);     // trunc
        by  = (int)((v1 + v2) * 0.5f);
        col = (hw <= hh) ? 1 : 0;
        float sigma = (float)(2 * r + 1) / 6.0f;
        two_s2 = 2.0f * sigma * sigma;
        keep = (bx + r >= x0s) && (bx - r <= x1s) &&
               (by + r >= y0s) && (by - r <= y1s);
    }
    unsigned long long m = __ballot(keep);
    if (t < NBOX && (t & 63) == 0) smask[t >> 6] = m;
    __syncthreads();
    if (t < NBOX) {
        const int w = t >> 6, lane = t & 63;
        const unsigned long long lm = smask[w];
        int off = __popcll(lm & ((1ull << lane) - 1ull));
        if (w) off += __popcll(smask[0]);
        if (keep) {
            sbx[off] = bx; sby[off] = by; sr[off] = r;
            scol[off] = col; s2s[off] = two_s2;
        }
        if (t == 0) nsel = __popcll(smask[0]) + __popcll(smask[1]);
    }
    __syncthreads();

    // ---- Stage B: evaluate surviving boxes for this thread's 4 pixels ----
    float acc[4] = {0.0f, 0.0f, 0.0f, 0.0f};
    if (row_ok && x0 < W_OUT) {
        const int py = y * 4;
        const int ns = nsel;
        for (int k = 0; k < ns; ++k) {
            const int dy = py - sby[k];
            const int rr = sr[k];
            if (dy > rr || dy < -rr) continue;
            const int hl  = rr >> 1;          // r//2
            const int hh2 = (rr + 1) >> 1;    // ceil(r/2)
            const int cl  = scol[k];
            if (!cl) {
                if (dy < -hh2 || dy >= hh2) continue;   // row band (dy-only)
            }
            const float ts2 = s2s[k];
            const int bxk = sbx[k];
            const float fdy2 = (float)(dy * dy);
            #pragma unroll
            for (int j = 0; j < 4; ++j) {
                const int dx = (x0 + j) * 4 - bxk;
                if (dx > rr || dx < -rr) continue;
                if (cl && (dx < -hl || dx >= hh2)) continue;   // col band
                const float d2 = (float)(dx * dx) + fdy2;
                const float g  = expf(-d2 / ts2);     // identical arithmetic (absmax 0)
                if (g >= EPS64F) acc[j] += g;
            }
        }
    }

    // ---- per-pixel loss, summed over this thread's valid pixels ----
    float sfg = 0.0f, sbg = 0.0f, snp = 0.0f;
    #pragma unroll
    for (int j = 0; j < 4; ++j) {
        const bool ok = row_ok && (x0 + j) < W_OUT;
        if (!ok) continue;
        const float fgs = fminf(fmaxf(acc[j], 0.0f), 1.0f);
        const bool  fgb = fgs > 0.5f;
        const float bgm = fgb ? 0.0f : 1.0f;
        const float w   = fgb ? 13.0f : 1.0f;
        const int   tgt = (int)fgs;           // 1 only where saturated to exactly 1.0

        const float mx  = fmaxf(pa[j], pb[j]);
        const float lse = mx + logf(expf(pa[j] - mx) + expf(pb[j] - mx));
        const float logpt = (tgt ? pb[j] : pa[j]) - lse;
        const float pt = expf(logpt);
        const float om = 1.0f - pt;
        const float loss = -0.25f * om * om * logpt * w;

        sfg += loss * fgs;
        sbg += loss * bgm;
        snp += fgs + bgm;
    }

    // block reduction: wave shuffle + cross-wave LDS (4 waves)
    for (int o = 32; o > 0; o >>= 1) {
        sfg += __shfl_down(sfg, o);
        sbg += __shfl_down(sbg, o);
        snp += __shfl_down(snp, o);
    }
    __shared__ float rfg[BS / 64], rbg[BS / 64], rnp[BS / 64];
    const int wave = t >> 6, lane = t & 63;
    if (lane == 0) { rfg[wave] = sfg; rbg[wave] = sbg; rnp[wave] = snp; }
    __syncthreads();
    if (t == 0) {
        float a1 = 0.f, a2 = 0.f, a3 = 0.f;
        for (int wv = 0; wv < BS / 64; ++wv) { a1 += rfg[wv]; a2 += rbg[wv]; a3 += rnp[wv]; }
        part[blockIdx.x]            = a1;
        part[NBLK + blockIdx.x]     = a2;
        part[2 * NBLK + blockIdx.x] = a3;
    }
}

__global__ __launch_bounds__(128) void segloss_final(
    const float* __restrict__ part, float* __restrict__ out)
{
    const int t = threadIdx.x;     // 2 waves, NBLK=104 < 128
    float f1 = 0.0f, f2 = 0.0f, f3 = 0.0f;
    if (t < NBLK) {
        f1 = part[t];
        f2 = part[NBLK + t];
        f3 = part[2 * NBLK + t];
    }
    for (int o = 32; o > 0; o >>= 1) {
        f1 += __shfl_down(f1, o);
        f2 += __shfl_down(f2, o);
        f3 += __shfl_down(f3, o);
    }
    __shared__ float r1[2], r2[2], r3[2];
    const int wave = t >> 6, lane = t & 63;
    if (lane == 0) { r1[wave] = f1; r2[wave] = f2; r3[wave] = f3; }
    __syncthreads();
    if (t == 0)
        out[0] = ((r1[0] + r1[1]) + (r2[0] + r2[1])) / (r3[0] + r3[1]);
}

extern "C" void kernel_launch(void* const* d_in, const int* in_sizes, int n_in,
                              void* d_out, int out_size, void* d_ws, size_t ws_size,
                              hipStream_t stream) {
    const float* boxes = (const float*)d_in[0];   // gt_boxes2d (128,4)
    // d_in[1] = images (900,1600): only its shape is used by the reference
    const float* pred  = (const float*)d_in[2];   // fg_pred (1,2,225,400)
    float* out  = (float*)d_out;
    float* part = (float*)d_ws;                   // 3*NBLK floats = 1248 B

    segloss_main<<<NBLK, BS, 0, stream>>>(boxes, pred, part);
    segloss_final<<<1, 128, 0, stream>>>(part, out);
}